// Round 2
// baseline (2838.445 us; speedup 1.0000x reference)
//
#include <hip/hip_runtime.h>

#define EMB_DIM   300
#define ROW_F4    75            // 300 floats = 75 float4
#define TAIL_F4   (ROW_F4 - 64) // 11 tail chunks, lanes 0..10
#define ROW_BYTES 1200
#define MAX_NB    8192          // bucket array reservation

// ---------------- workspace layout (ints) ----------------
// [0          .. S+1)        starts
// [32768      .. 32768+NB)   hist  (counts, then unused)
// [32768+8192 .. +NB)        cursor (exclusive prefix, bumped by scatter_rank)
// [32768+16384.. +T)         sw    (word indices in bucket-sorted order)
// total ~2.3 MB — harness ws (poisoned each iter, we rewrite everything we read)

__global__ __launch_bounds__(256) void zero_i32_kernel(int* __restrict__ p, int n) {
    int i = blockIdx.x * 256 + threadIdx.x;
    if (i < n) p[i] = 0;
}

__global__ __launch_bounds__(256) void zero_f4_kernel(float4* __restrict__ p, int n4) {
    int i = blockIdx.x * 256 + threadIdx.x;
    if (i < n4) p[i] = make_float4(0.f, 0.f, 0.f, 0.f);
}

// segment start offsets (seg ids sorted, every segment nonempty)
__global__ __launch_bounds__(256) void seg_starts_kernel(
        const int* __restrict__ seg, int T, int S, int* __restrict__ starts) {
    int t = blockIdx.x * 256 + threadIdx.x;
    if (t >= T) return;
    if (t == 0) {
        starts[0] = 0;
        starts[S] = T;
    } else if (seg[t] != seg[t - 1]) {
        starts[seg[t]] = t;
    }
}

__global__ __launch_bounds__(256) void hist_kernel(
        const int* __restrict__ ids, int T, int shift, int* __restrict__ hist) {
    int t = blockIdx.x * 256 + threadIdx.x;
    if (t < T) atomicAdd(&hist[((unsigned)ids[t]) >> shift], 1);
}

// single-block exclusive scan of NB (<= 8192) counts -> cursor
__global__ __launch_bounds__(1024) void scan_kernel(
        const int* __restrict__ hist, int* __restrict__ cursor, int NB) {
    __shared__ int part[1024];
    const int tid = threadIdx.x;
    int c[8];
    int sum = 0;
    const int base_i = tid * 8;
    #pragma unroll
    for (int k = 0; k < 8; ++k) {
        int i = base_i + k;
        c[k] = (i < NB) ? hist[i] : 0;
        sum += c[k];
    }
    part[tid] = sum;
    __syncthreads();
    // Hillis-Steele inclusive scan over 1024 partials
    for (int off = 1; off < 1024; off <<= 1) {
        int add = (tid >= off) ? part[tid - off] : 0;
        __syncthreads();
        part[tid] += add;
        __syncthreads();
    }
    int run = part[tid] - sum;   // exclusive prefix of this thread's chunk
    #pragma unroll
    for (int k = 0; k < 8; ++k) {
        int i = base_i + k;
        if (i < NB) cursor[i] = run;
        run += c[k];
    }
}

__global__ __launch_bounds__(256) void scatter_rank_kernel(
        const int* __restrict__ ids, int T, int shift,
        int* __restrict__ cursor, int* __restrict__ sw) {
    int t = blockIdx.x * 256 + threadIdx.x;
    if (t >= T) return;
    int b = ((unsigned)ids[t]) >> shift;
    int r = atomicAdd(&cursor[b], 1);
    sw[r] = t;
}

// bucket-major gather + atomic scatter-add. One wave handles 4 words.
__global__ __launch_bounds__(256) void scatter_add_kernel(
        const float* __restrict__ emb,
        const int*   __restrict__ ids,
        const int*   __restrict__ seg,
        const int*   __restrict__ sw,
        float*       __restrict__ out,
        int T) {
    const int lane = threadIdx.x & 63;
    const int wid  = threadIdx.x >> 6;
    const int base_rank = (blockIdx.x * 4 + wid) * 4;
    if (base_rank >= T) return;

    const bool tl = lane < TAIL_F4;
    const unsigned mainOff = (unsigned)lane * 16u;
    const unsigned tailOff = 1024u + (unsigned)(tl ? lane : (TAIL_F4 - 1)) * 16u;
    const char* embb = (const char*)emb;

    if (base_rank + 4 <= T) {                 // common path: full quad
        int tk[4], sg[4];
        const char* r[4];
        #pragma unroll
        for (int k = 0; k < 4; ++k) tk[k] = sw[base_rank + k];
        #pragma unroll
        for (int k = 0; k < 4; ++k) {
            sg[k] = seg[tk[k]];
            r[k]  = embb + (unsigned)ids[tk[k]] * (unsigned)ROW_BYTES;
        }
        float4 m[4], tt[4];
        #pragma unroll
        for (int k = 0; k < 4; ++k) {
            m[k]  = *(const float4*)(r[k] + mainOff);
            tt[k] = *(const float4*)(r[k] + tailOff);   // dup-lane read, coalesces
        }
        #pragma unroll
        for (int k = 0; k < 4; ++k) {
            float* __restrict__ orow = out + (size_t)sg[k] * EMB_DIM;
            atomicAdd(orow + lane * 4 + 0, m[k].x);
            atomicAdd(orow + lane * 4 + 1, m[k].y);
            atomicAdd(orow + lane * 4 + 2, m[k].z);
            atomicAdd(orow + lane * 4 + 3, m[k].w);
            if (tl) {   // predicated: a duplicated atomic would double-count
                atomicAdd(orow + 256 + lane * 4 + 0, tt[k].x);
                atomicAdd(orow + 256 + lane * 4 + 1, tt[k].y);
                atomicAdd(orow + 256 + lane * 4 + 2, tt[k].z);
                atomicAdd(orow + 256 + lane * 4 + 3, tt[k].w);
            }
        }
    } else {                                   // tail quad
        for (int k = 0; k < T - base_rank; ++k) {
            int t  = sw[base_rank + k];
            int sgk = seg[t];
            const char* r = embb + (unsigned)ids[t] * (unsigned)ROW_BYTES;
            float4 m  = *(const float4*)(r + mainOff);
            float4 tt = *(const float4*)(r + tailOff);
            float* __restrict__ orow = out + (size_t)sgk * EMB_DIM;
            atomicAdd(orow + lane * 4 + 0, m.x);
            atomicAdd(orow + lane * 4 + 1, m.y);
            atomicAdd(orow + lane * 4 + 2, m.z);
            atomicAdd(orow + lane * 4 + 3, m.w);
            if (tl) {
                atomicAdd(orow + 256 + lane * 4 + 0, tt.x);
                atomicAdd(orow + 256 + lane * 4 + 1, tt.y);
                atomicAdd(orow + 256 + lane * 4 + 2, tt.z);
                atomicAdd(orow + 256 + lane * 4 + 3, tt.w);
            }
        }
    }
}

// divide each segment's sum by its count. One wave per segment.
__global__ __launch_bounds__(256) void mean_kernel(
        const int* __restrict__ starts, float* __restrict__ out, int S) {
    const int lane = threadIdx.x & 63;
    const int s    = blockIdx.x * 4 + (threadIdx.x >> 6);
    if (s >= S) return;
    const float inv = 1.0f / (float)(starts[s + 1] - starts[s]);
    float4* __restrict__ orow = (float4*)(out + (size_t)s * EMB_DIM);
    float4 a = orow[lane];
    orow[lane] = make_float4(a.x * inv, a.y * inv, a.z * inv, a.w * inv);
    if (lane < TAIL_F4) {
        float4 b = orow[64 + lane];
        orow[64 + lane] = make_float4(b.x * inv, b.y * inv, b.z * inv, b.w * inv);
    }
}

extern "C" void kernel_launch(void* const* d_in, const int* in_sizes, int n_in,
                              void* d_out, int out_size, void* d_ws, size_t ws_size,
                              hipStream_t stream) {
    const float* emb      = (const float*)d_in[0];
    const int*   word_ids = (const int*)d_in[1];
    const int*   seg_ids  = (const int*)d_in[2];
    float* out = (float*)d_out;

    const int T = in_sizes[1];
    const int S = out_size / EMB_DIM;
    const int vocab = in_sizes[0] / EMB_DIM;

    int* W = (int*)d_ws;
    int* starts = W;                       // S+1
    int* hist   = W + 32768;               // NB
    int* cursor = W + 32768 + MAX_NB;      // NB
    int* sw     = W + 32768 + 2 * MAX_NB;  // T

    int shift = 7;
    while ((((unsigned)(vocab - 1)) >> shift) + 1 > MAX_NB) ++shift;
    const int NB = (((unsigned)(vocab - 1)) >> shift) + 1;

    zero_i32_kernel<<<(NB + 255) / 256, 256, 0, stream>>>(hist, NB);
    zero_f4_kernel<<<(S * ROW_F4 + 255) / 256, 256, 0, stream>>>(
        (float4*)out, S * ROW_F4);
    seg_starts_kernel<<<(T + 255) / 256, 256, 0, stream>>>(seg_ids, T, S, starts);
    hist_kernel<<<(T + 255) / 256, 256, 0, stream>>>(word_ids, T, shift, hist);
    scan_kernel<<<1, 1024, 0, stream>>>(hist, cursor, NB);
    scatter_rank_kernel<<<(T + 255) / 256, 256, 0, stream>>>(
        word_ids, T, shift, cursor, sw);

    const int nwaves = (T + 3) / 4;        // 4 words per wave
    scatter_add_kernel<<<(nwaves + 3) / 4, 256, 0, stream>>>(
        emb, word_ids, seg_ids, sw, out, T);

    mean_kernel<<<(S + 3) / 4, 256, 0, stream>>>(starts, out, S);
}